// Round 7
// baseline (156.372 us; speedup 1.0000x reference)
//
#include <hip/hip_runtime.h>
#include <cstdint>

// Radius NMS: B=4, C=4 (classes 1..3), N = 8192. Output: kept_coords
// [4,3,8192,2] f32 then keep [4,3,8192] f32, flat.
//
// ROUND 7: split kernels + parallel-fixpoint NMS with cheap rounds and a
// single-wave tail.
//   R5 ablation: phase 2 = 70 of 71 us (serial single-wave scan).
//   R6: exact-greedy fixpoint verified (absmax 0) but 94.7 us: depth is
//   ~O(log^2 n) ~ 100-150 rounds and each round paid 2 full-block
//   barriers; the tail (tens of points, ~100 levels) dominated.
// This round keeps the verified fixpoint phases (2a/2b/2c step logic
// verbatim) and restructures the schedule:
//   K1 (84 blocks): 72 blocks zero output; 12 blocks do phase 1
//      (argmax, stable compaction, cell precompute) -> workspace. [R5 vb]
//   K2 (12 blocks x 1024): build cell CSR + earlier-neighbor CSR in LDS,
//      then fixpoint with ONE barrier per bulk round (cnt[r&3] round-
//      robin counters, reset 2 ahead; per-wave ballot popcounts), and
//      when undecided <= 128: compact to tailList and let WAVE 0 finish
//      alone, wave-synchronously (volatile LDS reads, atomicOr writes,
//      ballot exit; no barriers). Lowest undecided rank always resolves
//      per sweep => termination. Kept bits packed to u64 via even-bit
//      compress and stored to workspace.
//   K3 (12 blocks): scatter kept coords/flags from workspace. [R5 vb]
// Fallback: R4 monolithic kernel (harness-verified) if ws too small.
//
// Numerics: fp contract OFF so dx*dx+dy*dy matches numpy (no FMA); argmax
// uses strict > (first-max tie-break like jnp.argmax). absmax=0 R0-R6.

#define NPTS 8192
#define CAP  2304          // candidates; M ~ Binom(8192,1/4) = 2048 +/- 39 (6.5 sigma)
#define R2C  9.0f
#define GW   56            // grid cells per dim
#define NCELL (GW * GW)    // 3136
#define GORG 117.6f        // grid covers [-117.6, 117.6), clamped beyond (3.92 sigma)
#define GINV 0.23809524f   // 1/4.2
#define GMAXC 55.0f
#define SENT 3.0e37f
#define NB_MAX 24576       // neighbor-edge capacity (expected ~5.3k)
#define TAIL_T 128         // switch to single-wave tail at <=128 undecided

// workspace layout, per problem p in 0..11 (stride 32 KB):
#define WS_STRIDE 32768
#define WS_XY     0         // float2[CAP]   18432 B
#define WS_CELL   18432     // u16[CAP]       4608 B
#define WS_OIDX   23040     // u16[CAP]       4608 B
#define WS_KEPT   27648     // u64[36]         288 B
#define WS_M      27936     // int
#define WS_NEED   (12 * WS_STRIDE)

// ---------------- K1: zero outputs + per-problem phase 1 (R5 verbatim) --
__global__ __launch_bounds__(1024) void k1_prep(
    const float* __restrict__ seg,    // [4,4,8192]
    const float* __restrict__ lidar,  // [4,5,8192]
    float* __restrict__ out,          // 294912 floats
    char* __restrict__ ws)
{
#pragma clang fp contract(off)
    const int blk = blockIdx.x;
    const int tid = threadIdx.x;
    if (blk >= 12) {
        ((float4*)out)[(size_t)(blk - 12) * 1024 + tid] =
            make_float4(0.f, 0.f, 0.f, 0.f);
        return;
    }
    const int b    = blk / 3;
    const int cls  = (blk % 3) + 1;
    const int lane = tid & 63;
    const int wv   = tid >> 6;     // 0..15
    __shared__ int waveTot[16];

    const float* segb = seg + (size_t)b * 4 * NPTS;
    const float* lx   = lidar + (size_t)b * 5 * NPTS;
    const float* ly   = lx + NPTS;

    const int n0 = tid * 8;
    const float4 a0 = *(const float4*)(segb + n0);
    const float4 a1 = *(const float4*)(segb + n0 + 4);
    const float4 b0 = *(const float4*)(segb + NPTS + n0);
    const float4 b1 = *(const float4*)(segb + NPTS + n0 + 4);
    const float4 c0 = *(const float4*)(segb + 2 * NPTS + n0);
    const float4 c1 = *(const float4*)(segb + 2 * NPTS + n0 + 4);
    const float4 d0 = *(const float4*)(segb + 3 * NPTS + n0);
    const float4 d1 = *(const float4*)(segb + 3 * NPTS + n0 + 4);
    const float4 xv0 = *(const float4*)(lx + n0);
    const float4 xv1 = *(const float4*)(lx + n0 + 4);
    const float4 yv0 = *(const float4*)(ly + n0);
    const float4 yv1 = *(const float4*)(ly + n0 + 4);

    const float v0[8] = {a0.x,a0.y,a0.z,a0.w, a1.x,a1.y,a1.z,a1.w};
    const float v1[8] = {b0.x,b0.y,b0.z,b0.w, b1.x,b1.y,b1.z,b1.w};
    const float v2[8] = {c0.x,c0.y,c0.z,c0.w, c1.x,c1.y,c1.z,c1.w};
    const float v3[8] = {d0.x,d0.y,d0.z,d0.w, d1.x,d1.y,d1.z,d1.w};
    const float px[8] = {xv0.x,xv0.y,xv0.z,xv0.w, xv1.x,xv1.y,xv1.z,xv1.w};
    const float py[8] = {yv0.x,yv0.y,yv0.z,yv0.w, yv1.x,yv1.y,yv1.z,yv1.w};

    int flags = 0, cnt = 0;
#pragma unroll
    for (int k = 0; k < 8; ++k) {
        int bi = 0; float bv = v0[k];
        if (v1[k] > bv) { bv = v1[k]; bi = 1; }
        if (v2[k] > bv) { bv = v2[k]; bi = 2; }
        if (v3[k] > bv) { bv = v3[k]; bi = 3; }
        if (bi == cls) { flags |= (1 << k); ++cnt; }
    }

    int v = cnt;
    for (int off = 1; off < 64; off <<= 1) {
        int nv = __shfl_up(v, off, 64);
        if (lane >= off) v += nv;
    }
    if (lane == 63) waveTot[wv] = v;
    __syncthreads();
    if (wv == 0) {
        int t = (lane < 16) ? waveTot[lane] : 0;
        for (int off = 1; off < 16; off <<= 1) {
            int nt = __shfl_up(t, off, 64);
            if (lane >= off) t += nt;
        }
        if (lane < 16) waveTot[lane] = t;
    }
    __syncthreads();

    int M = waveTot[15];
    if (M > CAP) M = CAP;

    char* wsp = ws + (size_t)blk * WS_STRIDE;
    float2* wxy = (float2*)(wsp + WS_XY);
    unsigned short* wcell = (unsigned short*)(wsp + WS_CELL);
    unsigned short* woidx = (unsigned short*)(wsp + WS_OIDX);
    if (tid == 0) *(int*)(wsp + WS_M) = M;

    int base = ((wv == 0) ? 0 : waveTot[wv - 1]) + v - cnt;
#pragma unroll
    for (int k = 0; k < 8; ++k) {
        if (flags & (1 << k)) {
            if (base < CAP) {
                wxy[base] = make_float2(px[k], py[k]);
                float fx = floorf((px[k] + GORG) * GINV);
                fx = fminf(fmaxf(fx, 0.0f), GMAXC);
                float fy = floorf((py[k] + GORG) * GINV);
                fy = fminf(fmaxf(fy, 0.0f), GMAXC);
                wcell[base] = (unsigned short)(((int)fy << 8) | (int)fx);
                woidx[base] = (unsigned short)(n0 + k);
            }
            ++base;
        }
    }
}

// ---------------- K2: parallel-fixpoint NMS -----------------------------
__global__ __launch_bounds__(1024) void k2_nms(char* __restrict__ ws)
{
#pragma clang fp contract(off)
    const int p    = blockIdx.x;   // 0..11
    const int tid  = threadIdx.x;
    const int lane = tid & 63;
    const int wv   = tid >> 6;     // 0..15

    char* wsp = ws + (size_t)p * WS_STRIDE;
    const float2* wxy = (const float2*)(wsp + WS_XY);
    const unsigned short* wcell = (const unsigned short*)(wsp + WS_CELL);
    unsigned long long* wkept = (unsigned long long*)(wsp + WS_KEPT);
    const int M = *(const int*)(wsp + WS_M);

    __shared__ float2 xy[CAP];
    __shared__ unsigned short cellOf[CAP];
    __shared__ unsigned short ptCSR[CAP];
    __shared__ unsigned short ncnt[CAP];
    __shared__ unsigned int   nStart[CAP];
    __shared__ unsigned int   cellCnt[NCELL];
    __shared__ unsigned int   cellStart[NCELL];
    __shared__ unsigned short nbr[NB_MAX];
    __shared__ unsigned int   statusW[CAP / 16];  // 2 bits/pt: b0=DEC b1=KEPT
    __shared__ int waveTot[16];
    __shared__ unsigned int cntRR[4];             // round-robin counters
    __shared__ int tailN;
    __shared__ unsigned short tailList[TAIL_T];

    // ---- load candidates + init ----
    for (int i = tid; i < M; i += 1024) {
        xy[i] = wxy[i];
        cellOf[i] = wcell[i];
    }
    for (int i = tid; i < NCELL; i += 1024) cellCnt[i] = 0u;
    for (int i = tid; i < CAP; i += 1024) ncnt[i] = 0;
    if (tid < CAP / 16) statusW[tid] = 0u;
    if (tid < 4) cntRR[tid] = 0u;
    if (tid == 0) tailN = 0;
    __syncthreads();

    // ---- 2a: bin candidates into cell CSR (R6 verbatim) ----
    for (int r = tid; r < M; r += 1024) {
        const int cc = cellOf[r];
        atomicAdd(&cellCnt[(cc >> 8) * GW + (cc & 255)], 1u);
    }
    __syncthreads();

    {   // exclusive scan cellCnt -> cellStart (4 cells/thread)
        const int c4 = tid * 4;
        int sa = 0, sb = 0, sc = 0, sd = 0;
        if (c4 < NCELL) {
            sa = cellCnt[c4]; sb = cellCnt[c4 + 1];
            sc = cellCnt[c4 + 2]; sd = cellCnt[c4 + 3];
        }
        int sum = sa + sb + sc + sd;
        int inc = sum;
        for (int off = 1; off < 64; off <<= 1) {
            int t = __shfl_up(inc, off, 64);
            if (lane >= off) inc += t;
        }
        if (lane == 63) waveTot[wv] = inc;
        __syncthreads();
        if (wv == 0) {
            int t = (lane < 16) ? waveTot[lane] : 0;
            for (int off = 1; off < 16; off <<= 1) {
                int u = __shfl_up(t, off, 64);
                if (lane >= off) t += u;
            }
            if (lane < 16) waveTot[lane] = t;
        }
        __syncthreads();
        const int bb = ((wv == 0) ? 0 : waveTot[wv - 1]) + inc - sum;
        if (c4 < NCELL) {
            cellStart[c4]     = bb;
            cellStart[c4 + 1] = bb + sa;
            cellStart[c4 + 2] = bb + sa + sb;
            cellStart[c4 + 3] = bb + sa + sb + sc;
        }
    }
    __syncthreads();

    for (int i = tid; i < NCELL; i += 1024) cellCnt[i] = 0u;
    __syncthreads();

    for (int r = tid; r < M; r += 1024) {
        const int cc = cellOf[r];
        const int c = (cc >> 8) * GW + (cc & 255);
        const unsigned pos = cellStart[c] + atomicAdd(&cellCnt[c], 1u);
        ptCSR[pos] = (unsigned short)r;
    }
    __syncthreads();

    // ---- 2b: earlier-neighbor CSR (R6 verbatim) ----
    for (int r = tid; r < M; r += 1024) {
        const float2 q = xy[r];
        const int cc = cellOf[r];
        const int cx = cc & 255, cy = cc >> 8;
        const int x0 = (cx > 0) ? cx - 1 : 0, x1 = (cx < GW - 1) ? cx + 1 : GW - 1;
        const int y0 = (cy > 0) ? cy - 1 : 0, y1 = (cy < GW - 1) ? cy + 1 : GW - 1;
        int nc = 0;
        for (int yy = y0; yy <= y1; ++yy)
            for (int xx = x0; xx <= x1; ++xx) {
                const int c = yy * GW + xx;
                const unsigned s = cellStart[c], n = cellCnt[c];
                for (unsigned k = 0; k < n; ++k) {
                    const int qr = ptCSR[s + k];
                    if (qr < r) {
                        const float2 o = xy[qr];
                        const float dx = q.x - o.x, dy = q.y - o.y;
                        if (dx * dx + dy * dy <= R2C) ++nc;
                    }
                }
            }
        ncnt[r] = (unsigned short)nc;
    }
    __syncthreads();

    {   // exclusive scan ncnt -> nStart (3 ranks/thread)
        const int r3 = tid * 3;
        int sa = 0, sb = 0, sc = 0;
        if (r3 < CAP) { sa = ncnt[r3]; sb = ncnt[r3 + 1]; sc = ncnt[r3 + 2]; }
        int sum = sa + sb + sc;
        int inc = sum;
        for (int off = 1; off < 64; off <<= 1) {
            int t = __shfl_up(inc, off, 64);
            if (lane >= off) inc += t;
        }
        if (lane == 63) waveTot[wv] = inc;
        __syncthreads();
        if (wv == 0) {
            int t = (lane < 16) ? waveTot[lane] : 0;
            for (int off = 1; off < 16; off <<= 1) {
                int u = __shfl_up(t, off, 64);
                if (lane >= off) t += u;
            }
            if (lane < 16) waveTot[lane] = t;
        }
        __syncthreads();
        const int bb = ((wv == 0) ? 0 : waveTot[wv - 1]) + inc - sum;
        if (r3 < CAP) {
            nStart[r3]     = bb;
            nStart[r3 + 1] = bb + sa;
            nStart[r3 + 2] = bb + sa + sb;
        }
    }
    __syncthreads();

    for (int r = tid; r < M; r += 1024) {
        const float2 q = xy[r];
        const int cc = cellOf[r];
        const int cx = cc & 255, cy = cc >> 8;
        const int x0 = (cx > 0) ? cx - 1 : 0, x1 = (cx < GW - 1) ? cx + 1 : GW - 1;
        const int y0 = (cy > 0) ? cy - 1 : 0, y1 = (cy < GW - 1) ? cy + 1 : GW - 1;
        unsigned pos = nStart[r];
        for (int yy = y0; yy <= y1; ++yy)
            for (int xx = x0; xx <= x1; ++xx) {
                const int c = yy * GW + xx;
                const unsigned s = cellStart[c], n = cellCnt[c];
                for (unsigned k = 0; k < n; ++k) {
                    const int qr = ptCSR[s + k];
                    if (qr < r) {
                        const float2 o = xy[qr];
                        const float dx = q.x - o.x, dy = q.y - o.y;
                        if (dx * dx + dy * dy <= R2C) {
                            if (pos < NB_MAX) nbr[pos] = (unsigned short)qr;
                            ++pos;
                        }
                    }
                }
            }
    }
    __syncthreads();

    // ---- 2c: fixpoint. bulk rounds (1 barrier each) then 1-wave tail ----
    unsigned resolvedMask = 0;
    unsigned st0 = 0, en0 = 0, st1 = 0, en1 = 0, st2 = 0, en2 = 0;
    { int r = tid;        if (r < M) { st0 = nStart[r]; en0 = st0 + ncnt[r]; if (en0 > NB_MAX) en0 = NB_MAX; } else resolvedMask |= 1u; }
    { int r = tid + 1024; if (r < M) { st1 = nStart[r]; en1 = st1 + ncnt[r]; if (en1 > NB_MAX) en1 = NB_MAX; } else resolvedMask |= 2u; }
    { int r = tid + 2048; if (r < M) { st2 = nStart[r]; en2 = st2 + ncnt[r]; if (en2 > NB_MAX) en2 = NB_MAX; } else resolvedMask |= 4u; }

    auto step = [&](int r, unsigned st, unsigned en) -> int {
        bool sup = false, allDec = true;
        for (unsigned k = st; k < en; ++k) {
            const int q = nbr[k];
            const unsigned f = (statusW[q >> 4] >> ((q & 15) * 2)) & 3u;
            if (f & 2u) { sup = true; break; }
            if (!(f & 1u)) allDec = false;
        }
        if (sup)    { atomicOr(&statusW[r >> 4], 1u << ((r & 15) * 2)); return 1; }
        if (allDec) { atomicOr(&statusW[r >> 4], 3u << ((r & 15) * 2)); return 1; }
        return 0;
    };

    bool needTail = false;
    for (int r = 0; ; ++r) {
        bool u0 = false, u1 = false, u2 = false;
        if (!(resolvedMask & 1u)) { if (step(tid,        st0, en0)) resolvedMask |= 1u; else u0 = true; }
        if (!(resolvedMask & 2u)) { if (step(tid + 1024, st1, en1)) resolvedMask |= 2u; else u1 = true; }
        if (!(resolvedMask & 4u)) { if (step(tid + 2048, st2, en2)) resolvedMask |= 4u; else u2 = true; }
        const unsigned long long b0 = __ballot(u0);
        const unsigned long long b1 = __ballot(u1);
        const unsigned long long b2 = __ballot(u2);
        if (lane == 0) {
            const unsigned c = __popcll(b0) + __popcll(b1) + __popcll(b2);
            if (c) atomicAdd(&cntRR[r & 3], c);
        }
        if (tid == 0) cntRR[(r + 2) & 3] = 0u;
        __syncthreads();
        const unsigned rem = cntRR[r & 3];
        if (rem == 0u) break;
        if (rem <= TAIL_T || r > 2500) { needTail = true; break; }
    }

    if (needTail) {
        // compact undecided ranks (owner threads only -> exact, <=TAIL_T)
        if (!(resolvedMask & 1u)) { int pos = atomicAdd(&tailN, 1); if (pos < TAIL_T) tailList[pos] = (unsigned short)tid; }
        if (!(resolvedMask & 2u)) { int pos = atomicAdd(&tailN, 1); if (pos < TAIL_T) tailList[pos] = (unsigned short)(tid + 1024); }
        if (!(resolvedMask & 4u)) { int pos = atomicAdd(&tailN, 1); if (pos < TAIL_T) tailList[pos] = (unsigned short)(tid + 2048); }
        __syncthreads();
        if (wv == 0) {
            int n = tailN; if (n > TAIL_T) n = TAIL_T;
            int ra = (lane < n) ? (int)tailList[lane] : -1;
            int rb = (lane + 64 < n) ? (int)tailList[lane + 64] : -1;
            bool da = (ra < 0), db = (rb < 0);
            unsigned sa = 0, ea = 0, sb = 0, eb = 0;
            if (!da) { sa = nStart[ra]; ea = sa + ncnt[ra]; if (ea > NB_MAX) ea = NB_MAX; }
            if (!db) { sb = nStart[rb]; eb = sb + ncnt[rb]; if (eb > NB_MAX) eb = NB_MAX; }
            volatile unsigned* vst = statusW;
            for (;;) {
                if (!da) {
                    bool sup = false, all = true;
                    for (unsigned k = sa; k < ea; ++k) {
                        const int q = nbr[k];
                        const unsigned f = (vst[q >> 4] >> ((q & 15) * 2)) & 3u;
                        if (f & 2u) { sup = true; break; }
                        if (!(f & 1u)) all = false;
                    }
                    if (sup)      { atomicOr(&statusW[ra >> 4], 1u << ((ra & 15) * 2)); da = true; }
                    else if (all) { atomicOr(&statusW[ra >> 4], 3u << ((ra & 15) * 2)); da = true; }
                }
                if (!db) {
                    bool sup = false, all = true;
                    for (unsigned k = sb; k < eb; ++k) {
                        const int q = nbr[k];
                        const unsigned f = (vst[q >> 4] >> ((q & 15) * 2)) & 3u;
                        if (f & 2u) { sup = true; break; }
                        if (!(f & 1u)) all = false;
                    }
                    if (sup)      { atomicOr(&statusW[rb >> 4], 1u << ((rb & 15) * 2)); db = true; }
                    else if (all) { atomicOr(&statusW[rb >> 4], 3u << ((rb & 15) * 2)); db = true; }
                }
                if (__ballot(!da || !db) == 0ull) break;
            }
        }
        __syncthreads();
    }

    // ---- pack kept bits -> u64[36] in workspace ----
    if (tid < CAP / 64) {
        unsigned long long w = 0ull;
#pragma unroll
        for (int j = 0; j < 4; ++j) {
            unsigned x = statusW[tid * 4 + j];
            x = (x >> 1) & 0x55555555u;            // kept bits to even pos
            x = (x | (x >> 1)) & 0x33333333u;
            x = (x | (x >> 2)) & 0x0F0F0F0Fu;
            x = (x | (x >> 4)) & 0x00FF00FFu;
            x = (x | (x >> 8)) & 0x0000FFFFu;      // 16-bit compress
            w |= (unsigned long long)x << (16 * j);
        }
        wkept[tid] = w;
    }
}

// ---------------- K3: scatter kept coords/flags (R5 verbatim) -----------
__global__ __launch_bounds__(1024) void k3_scatter(
    float* __restrict__ out, const char* __restrict__ ws)
{
    const int p   = blockIdx.x;
    const int tid = threadIdx.x;
    const char* wsp = ws + (size_t)p * WS_STRIDE;
    const float2* wxy = (const float2*)(wsp + WS_XY);
    const unsigned short* woidx = (const unsigned short*)(wsp + WS_OIDX);
    const unsigned long long* wkept =
        (const unsigned long long*)(wsp + WS_KEPT);
    const int M = *(const int*)(wsp + WS_M);

    float* out0 = out + (size_t)p * NPTS * 2;
    float* out1 = out + 196608 + (size_t)p * NPTS;
    for (int j = tid; j < M; j += 1024) {
        if ((wkept[j >> 6] >> (j & 63)) & 1ull) {
            const int n = woidx[j];
            float2 q = wxy[j];
            out0[2 * n]     = q.x;
            out0[2 * n + 1] = q.y;
            out1[n]         = 1.0f;
        }
    }
}

// ---------------- fallback: R4 monolithic (harness-verified) ------------
__global__ __launch_bounds__(1024) void radius_nms_fb(
    const float* __restrict__ seg,
    const float* __restrict__ lidar,
    float* __restrict__ out)
{
#pragma clang fp contract(off)
    const int bx   = blockIdx.x;
    const int b    = bx / 3;
    const int cls  = (bx % 3) + 1;
    const int tid  = threadIdx.x;
    const int lane = tid & 63;
    const int wv   = tid >> 6;

    __shared__ float2 xy[CAP];
    __shared__ unsigned short cellA[CAP];
    __shared__ unsigned long long keptW[CAP / 64];
    __shared__ int waveTot[16];
    __shared__ float2 gslot[GW * GW * 4];
    __shared__ unsigned int cnt32[(GW * GW + 3) / 4];

    float* out0 = out + (size_t)bx * NPTS * 2;
    float* out1 = out + 196608 + (size_t)bx * NPTS;

    const float4 z4 = make_float4(0.f, 0.f, 0.f, 0.f);
    float4* o04 = (float4*)out0;
    float4* o14 = (float4*)out1;
    for (int i = tid; i < NPTS / 2; i += 1024) o04[i] = z4;
    for (int i = tid; i < NPTS / 4; i += 1024) o14[i] = z4;
    const float2 s2 = make_float2(SENT, SENT);
    for (int i = tid; i < GW * GW * 4; i += 1024) gslot[i] = s2;
    for (int i = tid; i < (GW * GW + 3) / 4; i += 1024) cnt32[i] = 0u;

    const float* segb = seg + (size_t)b * 4 * NPTS;
    const float* lx   = lidar + (size_t)b * 5 * NPTS;
    const float* ly   = lx + NPTS;

    const int n0 = tid * 8;
    const float4 a0 = *(const float4*)(segb + n0);
    const float4 a1 = *(const float4*)(segb + n0 + 4);
    const float4 b0 = *(const float4*)(segb + NPTS + n0);
    const float4 b1 = *(const float4*)(segb + NPTS + n0 + 4);
    const float4 c0 = *(const float4*)(segb + 2 * NPTS + n0);
    const float4 c1 = *(const float4*)(segb + 2 * NPTS + n0 + 4);
    const float4 d0 = *(const float4*)(segb + 3 * NPTS + n0);
    const float4 d1 = *(const float4*)(segb + 3 * NPTS + n0 + 4);
    const float4 xv0 = *(const float4*)(lx + n0);
    const float4 xv1 = *(const float4*)(lx + n0 + 4);
    const float4 yv0 = *(const float4*)(ly + n0);
    const float4 yv1 = *(const float4*)(ly + n0 + 4);

    const float v0[8] = {a0.x,a0.y,a0.z,a0.w, a1.x,a1.y,a1.z,a1.w};
    const float v1[8] = {b0.x,b0.y,b0.z,b0.w, b1.x,b1.y,b1.z,b1.w};
    const float v2[8] = {c0.x,c0.y,c0.z,c0.w, c1.x,c1.y,c1.z,c1.w};
    const float v3[8] = {d0.x,d0.y,d0.z,d0.w, d1.x,d1.y,d1.z,d1.w};
    const float px[8] = {xv0.x,xv0.y,xv0.z,xv0.w, xv1.x,xv1.y,xv1.z,xv1.w};
    const float py[8] = {yv0.x,yv0.y,yv0.z,yv0.w, yv1.x,yv1.y,yv1.z,yv1.w};

    int flags = 0, cnt = 0;
#pragma unroll
    for (int k = 0; k < 8; ++k) {
        int bi = 0; float bv = v0[k];
        if (v1[k] > bv) { bv = v1[k]; bi = 1; }
        if (v2[k] > bv) { bv = v2[k]; bi = 2; }
        if (v3[k] > bv) { bv = v3[k]; bi = 3; }
        if (bi == cls) { flags |= (1 << k); ++cnt; }
    }

    int v = cnt;
    for (int off = 1; off < 64; off <<= 1) {
        int nv = __shfl_up(v, off, 64);
        if (lane >= off) v += nv;
    }
    if (lane == 63) waveTot[wv] = v;
    __syncthreads();
    if (wv == 0) {
        int t = (lane < 16) ? waveTot[lane] : 0;
        for (int off = 1; off < 16; off <<= 1) {
            int nt = __shfl_up(t, off, 64);
            if (lane >= off) t += nt;
        }
        if (lane < 16) waveTot[lane] = t;
    }
    __syncthreads();

    int M = waveTot[15];
    if (M > CAP) M = CAP;
    const int rank0 = ((wv == 0) ? 0 : waveTot[wv - 1]) + v - cnt;
    int base = rank0;
#pragma unroll
    for (int k = 0; k < 8; ++k) {
        if (flags & (1 << k)) {
            if (base < CAP) {
                xy[base] = make_float2(px[k], py[k]);
                float fx = floorf((px[k] + GORG) * GINV);
                fx = fminf(fmaxf(fx, 0.0f), GMAXC);
                float fy = floorf((py[k] + GORG) * GINV);
                fy = fminf(fmaxf(fy, 0.0f), GMAXC);
                cellA[base] = (unsigned short)(((int)fy << 8) | (int)fx);
            }
            ++base;
        }
    }
    __syncthreads();

    if (wv == 0) {
        const int ntiles = (M + 63) >> 6;
        const int packSent = (55 << 8) | 55;

        float qx = 3.0e38f, qy = 3.0e38f;
        int cc = packSent;
        if (lane < M) {
            float2 q = xy[lane]; qx = q.x; qy = q.y;
            cc = cellA[lane];
        }

        for (int t = 0; t < ntiles; ++t) {
            const int ts = t << 6;

            float qxN = 3.0e38f, qyN = 3.0e38f;
            int ccN = packSent;
            {
                const int p2 = ts + 64 + lane;
                if (p2 < M) {
                    float2 q = xy[p2]; qxN = q.x; qyN = q.y;
                    ccN = cellA[p2];
                }
            }

            const int cx = cc & 0xFF, cy = cc >> 8;
            const int cxm = (cx > 0) ? cx - 1 : 0;
            const int cxp = (cx < GW - 1) ? cx + 1 : GW - 1;
            const int rm  = ((cy > 0) ? cy - 1 : 0) * GW;
            const int r0  = cy * GW;
            const int rp  = ((cy < GW - 1) ? cy + 1 : GW - 1) * GW;
            const int cLin = r0 + cx;
            const int c9[9] = { rm + cxm, rm + cx, rm + cxp,
                                r0 + cxm, cLin,    r0 + cxp,
                                rp + cxm, rp + cx, rp + cxp };

            float mm = 1.0e30f;
#pragma unroll
            for (int i = 0; i < 9; ++i) {
                const int sb = c9[i] * 4;
                const float2 s0 = gslot[sb];
                const float2 s1 = gslot[sb + 1];
                const float2 s2r = gslot[sb + 2];
                const float2 s3 = gslot[sb + 3];
                float dx, dy;
                dx = qx - s0.x; dy = qy - s0.y; const float e0 = dx * dx + dy * dy;
                dx = qx - s1.x; dy = qy - s1.y; const float e1 = dx * dx + dy * dy;
                dx = qx - s2r.x; dy = qy - s2r.y; const float e2 = dx * dx + dy * dy;
                dx = qx - s3.x; dy = qy - s3.y; const float e3 = dx * dx + dy * dy;
                const float cm = fminf(fminf(e0, e1), fminf(e2, e3));
                mm = fminf(mm, cm);
            }
            const bool sup = (mm <= R2C);

            int cntT = M - ts; if (cntT > 64) cntT = 64;
            const unsigned long long tm =
                (cntT >= 64) ? ~0ull : ((1ull << cntT) - 1ull);
            unsigned long long alive = __ballot(!sup) & tm;
            unsigned long long keepm = 0ull;
            while (alive) {
                const int l = __builtin_ctzll(alive);
                const float xl = __int_as_float(
                    __builtin_amdgcn_readlane(__float_as_int(qx), l));
                const float yl = __int_as_float(
                    __builtin_amdgcn_readlane(__float_as_int(qy), l));
                const float dx = qx - xl;
                const float dy = qy - yl;
                unsigned long long b2 = __ballot((dx * dx + dy * dy) <= R2C);
                keepm |= (1ull << l);
                alive &= ~b2;
            }
            if (lane == 0) keptW[t] = keepm;

            if ((keepm >> lane) & 1ull) {
                const unsigned sh = 8u * (unsigned)(cLin & 3);
                unsigned old = atomicAdd(&cnt32[cLin >> 2], 1u << sh);
                unsigned mc = (old >> sh) & 0xFFu;
                if (mc < 4u) gslot[cLin * 4 + (int)mc] = make_float2(qx, qy);
            }

            qx = qxN; qy = qyN; cc = ccN;
        }
    }
    __syncthreads();

    int j = rank0;
#pragma unroll
    for (int k = 0; k < 8; ++k) {
        if (flags & (1 << k)) {
            if (j < M && ((keptW[j >> 6] >> (j & 63)) & 1ull)) {
                const int n = n0 + k;
                out0[2 * n]     = px[k];
                out0[2 * n + 1] = py[k];
                out1[n]         = 1.0f;
            }
            ++j;
        }
    }
}

extern "C" void kernel_launch(void* const* d_in, const int* in_sizes, int n_in,
                              void* d_out, int out_size, void* d_ws, size_t ws_size,
                              hipStream_t stream) {
    const float* seg   = (const float*)d_in[0];   // [4,4,64,128] f32
    const float* lidar = (const float*)d_in[1];   // [4,5,64,128] f32
    float* out = (float*)d_out;
    if (d_ws != nullptr && ws_size >= (size_t)WS_NEED) {
        char* ws = (char*)d_ws;
        k1_prep<<<dim3(84), dim3(1024), 0, stream>>>(seg, lidar, out, ws);
        k2_nms<<<dim3(12), dim3(1024), 0, stream>>>(ws);
        k3_scatter<<<dim3(12), dim3(1024), 0, stream>>>(out, ws);
    } else {
        radius_nms_fb<<<dim3(12), dim3(1024), 0, stream>>>(seg, lidar, out);
    }
}

// Round 8
// 154.465 us; speedup vs baseline: 1.0123x; 1.0123x over previous
//
#include <hip/hip_runtime.h>
#include <cstdint>

// Radius NMS: B=4, C=4 (classes 1..3), N = 8192. Output: kept_coords
// [4,3,8192,2] f32 then keep [4,3,8192] f32, flat.
//
// ROUND 8: hybrid phase-2 = parallel fixpoint (bulk) + serial scan (tail).
//   R5: serial single-wave scan = 70 us, ~5.3k cy per 64-pt tile,
//       independent of dependency depth.
//   R6/R7: parallel fixpoint = 95-97 us; cost ~ 1 us PER DEPENDENCY LEVEL
//       (~50 bulk rounds + ~70 tail sweeps), invariant to barrier count.
//   => use each machine where it wins: 24 FIXED fixpoint rounds decide the
//      bulk (~80-90% of points, no convergence bookkeeping: step+barrier
//      only), then compact undecided in RANK ORDER and finish with the
//      R5-verbatim serial readlane scan over just the tail (~4-9 tiles),
//      with the coord spatial-hash grid pre-populated with decided-KEPT
//      points (all inserted points are in the final kept set => the <=4
//      per 4.2m cell capacity proof holds; clamped monotone cell map =>
//      pruning sound; exact d^2<=9 decides).
//   LDS: grid (100KB) overlays the dead CSR region after the bulk rounds
//      (manual offsets in one smem array, 131,840 B total).
//   K1 (84 blocks): 72 zero output, 12 do phase 1 -> workspace. [R5 vb]
//   K3 (12 blocks): scatter kept coords/flags from workspace.   [R5 vb]
// Fallback: R4 monolithic kernel (harness-verified) if ws too small.
//
// Numerics: fp contract OFF so dx*dx+dy*dy matches numpy (no FMA); argmax
// uses strict > (first-max tie-break like jnp.argmax). absmax=0 R0-R7.

#define NPTS 8192
#define CAP  2304          // candidates; M ~ Binom(8192,1/4) = 2048 +/- 39 (6.5 sigma)
#define R2C  9.0f
#define GW   56            // grid cells per dim
#define NCELL (GW * GW)    // 3136
#define GORG 117.6f        // grid covers [-117.6, 117.6), clamped beyond (3.92 sigma)
#define GINV 0.23809524f   // 1/4.2
#define GMAXC 55.0f
#define SENT 3.0e37f
#define NB_MAX 24576       // neighbor-edge capacity (expected ~5.3k)
#define B_ROUNDS 24        // fixed bulk fixpoint rounds

// K2 LDS layout (manual offsets; region B overlaid by grid after bulk):
#define SM_XY      0                   // float2[2304]            18432
#define SM_CELL    18432               // u16[2304]    -> 23040
#define SM_STATUS  23040               // u32[144]     -> 23616  (2b/pt)
#define SM_WTOT    23616               // int[16]      -> 23680
#define SM_MISC    23680               // int[4]       -> 23696 (pad->23744)
#define SM_PTCSR   23744               // u16[2304]    -> 28352  [B]
#define SM_NCNT    28352               // u16[2304]    -> 32960  [B]
#define SM_NSTART  32960               // u32[2304]    -> 42176  [B]
#define SM_CCNT    42176               // u32[3136]    -> 54720  [B]
#define SM_CSTART  54720               // u32[3136]    -> 67264  [B]
#define SM_NBR     67264               // u16[24576]   -> 116416 [B]
#define SM_GSLOT   23744               // float2[12544]-> 124096 [overlays B]
#define SM_CNT32   124096              // u32[784]     -> 127232
#define SM_TAILIDX 127232              // u16[2304]    -> 131840
#define SM_TOTAL   131840

// workspace layout, per problem p in 0..11 (stride 32 KB):
#define WS_STRIDE 32768
#define WS_XY     0         // float2[CAP]   18432 B
#define WS_CELL   18432     // u16[CAP]       4608 B
#define WS_OIDX   23040     // u16[CAP]       4608 B
#define WS_KEPT   27648     // u64[36]         288 B
#define WS_M      27936     // int
#define WS_NEED   (12 * WS_STRIDE)

// ---------------- K1: zero outputs + per-problem phase 1 (R5 verbatim) --
__global__ __launch_bounds__(1024) void k1_prep(
    const float* __restrict__ seg,    // [4,4,8192]
    const float* __restrict__ lidar,  // [4,5,8192]
    float* __restrict__ out,          // 294912 floats
    char* __restrict__ ws)
{
#pragma clang fp contract(off)
    const int blk = blockIdx.x;
    const int tid = threadIdx.x;
    if (blk >= 12) {
        ((float4*)out)[(size_t)(blk - 12) * 1024 + tid] =
            make_float4(0.f, 0.f, 0.f, 0.f);
        return;
    }
    const int b    = blk / 3;
    const int cls  = (blk % 3) + 1;
    const int lane = tid & 63;
    const int wv   = tid >> 6;     // 0..15
    __shared__ int waveTot[16];

    const float* segb = seg + (size_t)b * 4 * NPTS;
    const float* lx   = lidar + (size_t)b * 5 * NPTS;
    const float* ly   = lx + NPTS;

    const int n0 = tid * 8;
    const float4 a0 = *(const float4*)(segb + n0);
    const float4 a1 = *(const float4*)(segb + n0 + 4);
    const float4 b0 = *(const float4*)(segb + NPTS + n0);
    const float4 b1 = *(const float4*)(segb + NPTS + n0 + 4);
    const float4 c0 = *(const float4*)(segb + 2 * NPTS + n0);
    const float4 c1 = *(const float4*)(segb + 2 * NPTS + n0 + 4);
    const float4 d0 = *(const float4*)(segb + 3 * NPTS + n0);
    const float4 d1 = *(const float4*)(segb + 3 * NPTS + n0 + 4);
    const float4 xv0 = *(const float4*)(lx + n0);
    const float4 xv1 = *(const float4*)(lx + n0 + 4);
    const float4 yv0 = *(const float4*)(ly + n0);
    const float4 yv1 = *(const float4*)(ly + n0 + 4);

    const float v0[8] = {a0.x,a0.y,a0.z,a0.w, a1.x,a1.y,a1.z,a1.w};
    const float v1[8] = {b0.x,b0.y,b0.z,b0.w, b1.x,b1.y,b1.z,b1.w};
    const float v2[8] = {c0.x,c0.y,c0.z,c0.w, c1.x,c1.y,c1.z,c1.w};
    const float v3[8] = {d0.x,d0.y,d0.z,d0.w, d1.x,d1.y,d1.z,d1.w};
    const float px[8] = {xv0.x,xv0.y,xv0.z,xv0.w, xv1.x,xv1.y,xv1.z,xv1.w};
    const float py[8] = {yv0.x,yv0.y,yv0.z,yv0.w, yv1.x,yv1.y,yv1.z,yv1.w};

    int flags = 0, cnt = 0;
#pragma unroll
    for (int k = 0; k < 8; ++k) {
        int bi = 0; float bv = v0[k];
        if (v1[k] > bv) { bv = v1[k]; bi = 1; }
        if (v2[k] > bv) { bv = v2[k]; bi = 2; }
        if (v3[k] > bv) { bv = v3[k]; bi = 3; }
        if (bi == cls) { flags |= (1 << k); ++cnt; }
    }

    int v = cnt;
    for (int off = 1; off < 64; off <<= 1) {
        int nv = __shfl_up(v, off, 64);
        if (lane >= off) v += nv;
    }
    if (lane == 63) waveTot[wv] = v;
    __syncthreads();
    if (wv == 0) {
        int t = (lane < 16) ? waveTot[lane] : 0;
        for (int off = 1; off < 16; off <<= 1) {
            int nt = __shfl_up(t, off, 64);
            if (lane >= off) t += nt;
        }
        if (lane < 16) waveTot[lane] = t;
    }
    __syncthreads();

    int M = waveTot[15];
    if (M > CAP) M = CAP;

    char* wsp = ws + (size_t)blk * WS_STRIDE;
    float2* wxy = (float2*)(wsp + WS_XY);
    unsigned short* wcell = (unsigned short*)(wsp + WS_CELL);
    unsigned short* woidx = (unsigned short*)(wsp + WS_OIDX);
    if (tid == 0) *(int*)(wsp + WS_M) = M;

    int base = ((wv == 0) ? 0 : waveTot[wv - 1]) + v - cnt;
#pragma unroll
    for (int k = 0; k < 8; ++k) {
        if (flags & (1 << k)) {
            if (base < CAP) {
                wxy[base] = make_float2(px[k], py[k]);
                float fx = floorf((px[k] + GORG) * GINV);
                fx = fminf(fmaxf(fx, 0.0f), GMAXC);
                float fy = floorf((py[k] + GORG) * GINV);
                fy = fminf(fmaxf(fy, 0.0f), GMAXC);
                wcell[base] = (unsigned short)(((int)fy << 8) | (int)fx);
                woidx[base] = (unsigned short)(n0 + k);
            }
            ++base;
        }
    }
}

// ---------------- K2: hybrid fixpoint + serial-tail NMS -----------------
__global__ __launch_bounds__(1024) void k2_nms(char* __restrict__ ws)
{
#pragma clang fp contract(off)
    const int p    = blockIdx.x;   // 0..11
    const int tid  = threadIdx.x;
    const int lane = tid & 63;
    const int wv   = tid >> 6;     // 0..15

    char* wsp = ws + (size_t)p * WS_STRIDE;
    const float2* wxy = (const float2*)(wsp + WS_XY);
    const unsigned short* wcell = (const unsigned short*)(wsp + WS_CELL);
    unsigned long long* wkept = (unsigned long long*)(wsp + WS_KEPT);
    const int M = *(const int*)(wsp + WS_M);

    __shared__ char smem[SM_TOTAL];
    float2*         xy      = (float2*)(smem + SM_XY);
    unsigned short* cellOf  = (unsigned short*)(smem + SM_CELL);
    unsigned int*   statusW = (unsigned int*)(smem + SM_STATUS);
    int*            waveTot = (int*)(smem + SM_WTOT);
    unsigned short* ptCSR   = (unsigned short*)(smem + SM_PTCSR);
    unsigned short* ncnt    = (unsigned short*)(smem + SM_NCNT);
    unsigned int*   nStart  = (unsigned int*)(smem + SM_NSTART);
    unsigned int*   cellCnt = (unsigned int*)(smem + SM_CCNT);
    unsigned int*   cellStart = (unsigned int*)(smem + SM_CSTART);
    unsigned short* nbr     = (unsigned short*)(smem + SM_NBR);
    float2*         gslot   = (float2*)(smem + SM_GSLOT);
    unsigned int*   cnt32   = (unsigned int*)(smem + SM_CNT32);
    unsigned short* tailIdx = (unsigned short*)(smem + SM_TAILIDX);

    // ---- load candidates + init ----
    for (int i = tid; i < M; i += 1024) {
        xy[i] = wxy[i];
        cellOf[i] = wcell[i];
    }
    for (int i = tid; i < NCELL; i += 1024) cellCnt[i] = 0u;
    if (tid < CAP / 16) statusW[tid] = 0u;
    __syncthreads();

    // ---- 2a: bin candidates into cell CSR (R6/R7 verbatim) ----
    for (int r = tid; r < M; r += 1024) {
        const int cc = cellOf[r];
        atomicAdd(&cellCnt[(cc >> 8) * GW + (cc & 255)], 1u);
    }
    __syncthreads();

    {   // exclusive scan cellCnt -> cellStart (4 cells/thread)
        const int c4 = tid * 4;
        int sa = 0, sb = 0, sc = 0, sd = 0;
        if (c4 < NCELL) {
            sa = cellCnt[c4]; sb = cellCnt[c4 + 1];
            sc = cellCnt[c4 + 2]; sd = cellCnt[c4 + 3];
        }
        int sum = sa + sb + sc + sd;
        int inc = sum;
        for (int off = 1; off < 64; off <<= 1) {
            int t = __shfl_up(inc, off, 64);
            if (lane >= off) inc += t;
        }
        if (lane == 63) waveTot[wv] = inc;
        __syncthreads();
        if (wv == 0) {
            int t = (lane < 16) ? waveTot[lane] : 0;
            for (int off = 1; off < 16; off <<= 1) {
                int u = __shfl_up(t, off, 64);
                if (lane >= off) t += u;
            }
            if (lane < 16) waveTot[lane] = t;
        }
        __syncthreads();
        const int bb = ((wv == 0) ? 0 : waveTot[wv - 1]) + inc - sum;
        if (c4 < NCELL) {
            cellStart[c4]     = bb;
            cellStart[c4 + 1] = bb + sa;
            cellStart[c4 + 2] = bb + sa + sb;
            cellStart[c4 + 3] = bb + sa + sb + sc;
        }
    }
    __syncthreads();

    for (int i = tid; i < NCELL; i += 1024) cellCnt[i] = 0u;
    __syncthreads();

    for (int r = tid; r < M; r += 1024) {
        const int cc = cellOf[r];
        const int c = (cc >> 8) * GW + (cc & 255);
        const unsigned pos = cellStart[c] + atomicAdd(&cellCnt[c], 1u);
        ptCSR[pos] = (unsigned short)r;
    }
    __syncthreads();

    // ---- 2b: earlier-neighbor CSR (R6/R7 verbatim) ----
    for (int r = tid; r < M; r += 1024) {
        const float2 q = xy[r];
        const int cc = cellOf[r];
        const int cx = cc & 255, cy = cc >> 8;
        const int x0 = (cx > 0) ? cx - 1 : 0, x1 = (cx < GW - 1) ? cx + 1 : GW - 1;
        const int y0 = (cy > 0) ? cy - 1 : 0, y1 = (cy < GW - 1) ? cy + 1 : GW - 1;
        int nc = 0;
        for (int yy = y0; yy <= y1; ++yy)
            for (int xx = x0; xx <= x1; ++xx) {
                const int c = yy * GW + xx;
                const unsigned s = cellStart[c], n = cellCnt[c];
                for (unsigned k = 0; k < n; ++k) {
                    const int qr = ptCSR[s + k];
                    if (qr < r) {
                        const float2 o = xy[qr];
                        const float dx = q.x - o.x, dy = q.y - o.y;
                        if (dx * dx + dy * dy <= R2C) ++nc;
                    }
                }
            }
        ncnt[r] = (unsigned short)nc;
    }
    __syncthreads();

    {   // exclusive scan ncnt -> nStart (3 ranks/thread)
        const int r3 = tid * 3;
        int sa = 0, sb = 0, sc = 0;
        if (r3 < CAP) { sa = ncnt[r3]; sb = ncnt[r3 + 1]; sc = ncnt[r3 + 2]; }
        int sum = sa + sb + sc;
        int inc = sum;
        for (int off = 1; off < 64; off <<= 1) {
            int t = __shfl_up(inc, off, 64);
            if (lane >= off) inc += t;
        }
        if (lane == 63) waveTot[wv] = inc;
        __syncthreads();
        if (wv == 0) {
            int t = (lane < 16) ? waveTot[lane] : 0;
            for (int off = 1; off < 16; off <<= 1) {
                int u = __shfl_up(t, off, 64);
                if (lane >= off) t += u;
            }
            if (lane < 16) waveTot[lane] = t;
        }
        __syncthreads();
        const int bb = ((wv == 0) ? 0 : waveTot[wv - 1]) + inc - sum;
        if (r3 < CAP) {
            nStart[r3]     = bb;
            nStart[r3 + 1] = bb + sa;
            nStart[r3 + 2] = bb + sa + sb;
        }
    }
    __syncthreads();

    for (int r = tid; r < M; r += 1024) {
        const float2 q = xy[r];
        const int cc = cellOf[r];
        const int cx = cc & 255, cy = cc >> 8;
        const int x0 = (cx > 0) ? cx - 1 : 0, x1 = (cx < GW - 1) ? cx + 1 : GW - 1;
        const int y0 = (cy > 0) ? cy - 1 : 0, y1 = (cy < GW - 1) ? cy + 1 : GW - 1;
        unsigned pos = nStart[r];
        for (int yy = y0; yy <= y1; ++yy)
            for (int xx = x0; xx <= x1; ++xx) {
                const int c = yy * GW + xx;
                const unsigned s = cellStart[c], n = cellCnt[c];
                for (unsigned k = 0; k < n; ++k) {
                    const int qr = ptCSR[s + k];
                    if (qr < r) {
                        const float2 o = xy[qr];
                        const float dx = q.x - o.x, dy = q.y - o.y;
                        if (dx * dx + dy * dy <= R2C) {
                            if (pos < NB_MAX) nbr[pos] = (unsigned short)qr;
                            ++pos;
                        }
                    }
                }
            }
    }
    __syncthreads();

    // ---- 2c: B_ROUNDS fixed bulk fixpoint rounds (step + barrier only) ----
    unsigned resolvedMask = 0;
    unsigned st0 = 0, en0 = 0, st1 = 0, en1 = 0, st2 = 0, en2 = 0;
    { int r = tid;        if (r < M) { st0 = nStart[r]; en0 = st0 + ncnt[r]; if (en0 > NB_MAX) en0 = NB_MAX; } else resolvedMask |= 1u; }
    { int r = tid + 1024; if (r < M) { st1 = nStart[r]; en1 = st1 + ncnt[r]; if (en1 > NB_MAX) en1 = NB_MAX; } else resolvedMask |= 2u; }
    { int r = tid + 2048; if (r < M) { st2 = nStart[r]; en2 = st2 + ncnt[r]; if (en2 > NB_MAX) en2 = NB_MAX; } else resolvedMask |= 4u; }

    auto step = [&](int r, unsigned st, unsigned en) -> int {
        bool sup = false, allDec = true;
        for (unsigned k = st; k < en; ++k) {
            const int q = nbr[k];
            const unsigned f = (statusW[q >> 4] >> ((q & 15) * 2)) & 3u;
            if (f & 2u) { sup = true; break; }
            if (!(f & 1u)) allDec = false;
        }
        if (sup)    { atomicOr(&statusW[r >> 4], 1u << ((r & 15) * 2)); return 1; }
        if (allDec) { atomicOr(&statusW[r >> 4], 3u << ((r & 15) * 2)); return 1; }
        return 0;
    };

    for (int r = 0; r < B_ROUNDS; ++r) {
        if (!(resolvedMask & 1u)) { if (step(tid,        st0, en0)) resolvedMask |= 1u; }
        if (!(resolvedMask & 2u)) { if (step(tid + 1024, st1, en1)) resolvedMask |= 2u; }
        if (!(resolvedMask & 4u)) { if (step(tid + 2048, st2, en2)) resolvedMask |= 4u; }
        __syncthreads();
    }
    // region B (ptCSR/ncnt/nStart/cellCnt/cellStart/nbr) is DEAD from here.

    // ---- grid init (overlays region B) + stable tail compaction ----
    {
        const float2 s2v = make_float2(SENT, SENT);
        for (int i = tid; i < NCELL * 4; i += 1024) gslot[i] = s2v;
        for (int i = tid; i < (NCELL + 3) / 4; i += 1024) cnt32[i] = 0u;
    }
    int base = 0;
    for (int c = 0; c < 3; ++c) {          // ranks c*1024 + tid, rank-stable
        const int r = c * 1024 + tid;
        int flag = 0;
        if (r < M) {
            const unsigned f = (statusW[r >> 4] >> ((r & 15) * 2)) & 3u;
            flag = ((f & 1u) == 0u) ? 1 : 0;   // undecided
        }
        int v = flag;
        for (int off = 1; off < 64; off <<= 1) {
            int nv = __shfl_up(v, off, 64);
            if (lane >= off) v += nv;
        }
        if (lane == 63) waveTot[wv] = v;
        __syncthreads();
        if (wv == 0) {
            int t = (lane < 16) ? waveTot[lane] : 0;
            for (int off = 1; off < 16; off <<= 1) {
                int u = __shfl_up(t, off, 64);
                if (lane >= off) t += u;
            }
            if (lane < 16) waveTot[lane] = t;
        }
        __syncthreads();
        const int pos = base + ((wv == 0) ? 0 : waveTot[wv - 1]) + v - flag;
        if (flag) tailIdx[pos] = (unsigned short)r;
        base += waveTot[15];
        __syncthreads();
    }
    const int ntail = base;

    // ---- insert decided-KEPT points into the grid ----
    for (int r = tid; r < M; r += 1024) {
        const unsigned f = (statusW[r >> 4] >> ((r & 15) * 2)) & 3u;
        if (f & 2u) {
            const int cc = cellOf[r];
            const int c = (cc >> 8) * GW + (cc & 255);
            const unsigned sh = 8u * (unsigned)(c & 3);
            const unsigned old = atomicAdd(&cnt32[c >> 2], 1u << sh);
            const unsigned mc = (old >> sh) & 0xFFu;
            if (mc < 4u) gslot[c * 4 + (int)mc] = xy[r];
        }
    }
    __syncthreads();

    // ---- serial readlane scan over the compacted tail (wave 0 only) ----
    if (wv == 0 && ntail > 0) {
        const int ntiles = (ntail + 63) >> 6;
        for (int t = 0; t < ntiles; ++t) {
            const int ts = t << 6;
            const int pp = ts + lane;
            float qx = 3.0e38f, qy = 3.0e38f;
            int cc = (55 << 8) | 55;
            int rr = 0;
            if (pp < ntail) {
                rr = tailIdx[pp];
                float2 q = xy[rr]; qx = q.x; qy = q.y;
                cc = cellOf[rr];
            }

            const int cx = cc & 0xFF, cy = cc >> 8;
            const int cxm = (cx > 0) ? cx - 1 : 0;
            const int cxp = (cx < GW - 1) ? cx + 1 : GW - 1;
            const int rm  = ((cy > 0) ? cy - 1 : 0) * GW;
            const int r0  = cy * GW;
            const int rp  = ((cy < GW - 1) ? cy + 1 : GW - 1) * GW;
            const int cLin = r0 + cx;
            const int c9[9] = { rm + cxm, rm + cx, rm + cxp,
                                r0 + cxm, cLin,    r0 + cxp,
                                rp + cxm, rp + cx, rp + cxp };

            float mm = 1.0e30f;
#pragma unroll
            for (int i = 0; i < 9; ++i) {
                const int sb = c9[i] * 4;
                const float2 s0 = gslot[sb];
                const float2 s1 = gslot[sb + 1];
                const float2 s2r = gslot[sb + 2];
                const float2 s3 = gslot[sb + 3];
                float dx, dy;
                dx = qx - s0.x; dy = qy - s0.y; const float e0 = dx * dx + dy * dy;
                dx = qx - s1.x; dy = qy - s1.y; const float e1 = dx * dx + dy * dy;
                dx = qx - s2r.x; dy = qy - s2r.y; const float e2 = dx * dx + dy * dy;
                dx = qx - s3.x; dy = qy - s3.y; const float e3 = dx * dx + dy * dy;
                const float cm = fminf(fminf(e0, e1), fminf(e2, e3));
                mm = fminf(mm, cm);
            }
            const bool sup = (mm <= R2C);

            int cntT = ntail - ts; if (cntT > 64) cntT = 64;
            const unsigned long long tm =
                (cntT >= 64) ? ~0ull : ((1ull << cntT) - 1ull);
            unsigned long long alive = __ballot(!sup) & tm;
            unsigned long long keepm = 0ull;
            while (alive) {
                const int l = __builtin_ctzll(alive);
                const float xl = __int_as_float(
                    __builtin_amdgcn_readlane(__float_as_int(qx), l));
                const float yl = __int_as_float(
                    __builtin_amdgcn_readlane(__float_as_int(qy), l));
                const float dx = qx - xl;
                const float dy = qy - yl;
                unsigned long long b2 = __ballot((dx * dx + dy * dy) <= R2C);
                keepm |= (1ull << l);
                alive &= ~b2;   // clears l (d2=0) and in-radius later points
            }

            if ((keepm >> lane) & 1ull) {
                atomicOr(&statusW[rr >> 4], 3u << ((rr & 15) * 2));
                const unsigned sh = 8u * (unsigned)(cLin & 3);
                unsigned old = atomicAdd(&cnt32[cLin >> 2], 1u << sh);
                unsigned mc = (old >> sh) & 0xFFu;
                if (mc < 4u) gslot[cLin * 4 + (int)mc] = make_float2(qx, qy);
            }
        }
    }
    __syncthreads();

    // ---- pack kept bits -> u64[36] in workspace (R7 verbatim) ----
    if (tid < CAP / 64) {
        unsigned long long w = 0ull;
#pragma unroll
        for (int j = 0; j < 4; ++j) {
            unsigned x = statusW[tid * 4 + j];
            x = (x >> 1) & 0x55555555u;            // kept bits to even pos
            x = (x | (x >> 1)) & 0x33333333u;
            x = (x | (x >> 2)) & 0x0F0F0F0Fu;
            x = (x | (x >> 4)) & 0x00FF00FFu;
            x = (x | (x >> 8)) & 0x0000FFFFu;      // 16-bit compress
            w |= (unsigned long long)x << (16 * j);
        }
        wkept[tid] = w;
    }
}

// ---------------- K3: scatter kept coords/flags (R5 verbatim) -----------
__global__ __launch_bounds__(1024) void k3_scatter(
    float* __restrict__ out, const char* __restrict__ ws)
{
    const int p   = blockIdx.x;
    const int tid = threadIdx.x;
    const char* wsp = ws + (size_t)p * WS_STRIDE;
    const float2* wxy = (const float2*)(wsp + WS_XY);
    const unsigned short* woidx = (const unsigned short*)(wsp + WS_OIDX);
    const unsigned long long* wkept =
        (const unsigned long long*)(wsp + WS_KEPT);
    const int M = *(const int*)(wsp + WS_M);

    float* out0 = out + (size_t)p * NPTS * 2;
    float* out1 = out + 196608 + (size_t)p * NPTS;
    for (int j = tid; j < M; j += 1024) {
        if ((wkept[j >> 6] >> (j & 63)) & 1ull) {
            const int n = woidx[j];
            float2 q = wxy[j];
            out0[2 * n]     = q.x;
            out0[2 * n + 1] = q.y;
            out1[n]         = 1.0f;
        }
    }
}

// ---------------- fallback: R4 monolithic (harness-verified) ------------
__global__ __launch_bounds__(1024) void radius_nms_fb(
    const float* __restrict__ seg,
    const float* __restrict__ lidar,
    float* __restrict__ out)
{
#pragma clang fp contract(off)
    const int bx   = blockIdx.x;
    const int b    = bx / 3;
    const int cls  = (bx % 3) + 1;
    const int tid  = threadIdx.x;
    const int lane = tid & 63;
    const int wv   = tid >> 6;

    __shared__ float2 xy[CAP];
    __shared__ unsigned short cellA[CAP];
    __shared__ unsigned long long keptW[CAP / 64];
    __shared__ int waveTot[16];
    __shared__ float2 gslot[GW * GW * 4];
    __shared__ unsigned int cnt32[(GW * GW + 3) / 4];

    float* out0 = out + (size_t)bx * NPTS * 2;
    float* out1 = out + 196608 + (size_t)bx * NPTS;

    const float4 z4 = make_float4(0.f, 0.f, 0.f, 0.f);
    float4* o04 = (float4*)out0;
    float4* o14 = (float4*)out1;
    for (int i = tid; i < NPTS / 2; i += 1024) o04[i] = z4;
    for (int i = tid; i < NPTS / 4; i += 1024) o14[i] = z4;
    const float2 s2 = make_float2(SENT, SENT);
    for (int i = tid; i < GW * GW * 4; i += 1024) gslot[i] = s2;
    for (int i = tid; i < (GW * GW + 3) / 4; i += 1024) cnt32[i] = 0u;

    const float* segb = seg + (size_t)b * 4 * NPTS;
    const float* lx   = lidar + (size_t)b * 5 * NPTS;
    const float* ly   = lx + NPTS;

    const int n0 = tid * 8;
    const float4 a0 = *(const float4*)(segb + n0);
    const float4 a1 = *(const float4*)(segb + n0 + 4);
    const float4 b0 = *(const float4*)(segb + NPTS + n0);
    const float4 b1 = *(const float4*)(segb + NPTS + n0 + 4);
    const float4 c0 = *(const float4*)(segb + 2 * NPTS + n0);
    const float4 c1 = *(const float4*)(segb + 2 * NPTS + n0 + 4);
    const float4 d0 = *(const float4*)(segb + 3 * NPTS + n0);
    const float4 d1 = *(const float4*)(segb + 3 * NPTS + n0 + 4);
    const float4 xv0 = *(const float4*)(lx + n0);
    const float4 xv1 = *(const float4*)(lx + n0 + 4);
    const float4 yv0 = *(const float4*)(ly + n0);
    const float4 yv1 = *(const float4*)(ly + n0 + 4);

    const float v0[8] = {a0.x,a0.y,a0.z,a0.w, a1.x,a1.y,a1.z,a1.w};
    const float v1[8] = {b0.x,b0.y,b0.z,b0.w, b1.x,b1.y,b1.z,b1.w};
    const float v2[8] = {c0.x,c0.y,c0.z,c0.w, c1.x,c1.y,c1.z,c1.w};
    const float v3[8] = {d0.x,d0.y,d0.z,d0.w, d1.x,d1.y,d1.z,d1.w};
    const float px[8] = {xv0.x,xv0.y,xv0.z,xv0.w, xv1.x,xv1.y,xv1.z,xv1.w};
    const float py[8] = {yv0.x,yv0.y,yv0.z,yv0.w, yv1.x,yv1.y,yv1.z,yv1.w};

    int flags = 0, cnt = 0;
#pragma unroll
    for (int k = 0; k < 8; ++k) {
        int bi = 0; float bv = v0[k];
        if (v1[k] > bv) { bv = v1[k]; bi = 1; }
        if (v2[k] > bv) { bv = v2[k]; bi = 2; }
        if (v3[k] > bv) { bv = v3[k]; bi = 3; }
        if (bi == cls) { flags |= (1 << k); ++cnt; }
    }

    int v = cnt;
    for (int off = 1; off < 64; off <<= 1) {
        int nv = __shfl_up(v, off, 64);
        if (lane >= off) v += nv;
    }
    if (lane == 63) waveTot[wv] = v;
    __syncthreads();
    if (wv == 0) {
        int t = (lane < 16) ? waveTot[lane] : 0;
        for (int off = 1; off < 16; off <<= 1) {
            int nt = __shfl_up(t, off, 64);
            if (lane >= off) t += nt;
        }
        if (lane < 16) waveTot[lane] = t;
    }
    __syncthreads();

    int M = waveTot[15];
    if (M > CAP) M = CAP;
    const int rank0 = ((wv == 0) ? 0 : waveTot[wv - 1]) + v - cnt;
    int base = rank0;
#pragma unroll
    for (int k = 0; k < 8; ++k) {
        if (flags & (1 << k)) {
            if (base < CAP) {
                xy[base] = make_float2(px[k], py[k]);
                float fx = floorf((px[k] + GORG) * GINV);
                fx = fminf(fmaxf(fx, 0.0f), GMAXC);
                float fy = floorf((py[k] + GORG) * GINV);
                fy = fminf(fmaxf(fy, 0.0f), GMAXC);
                cellA[base] = (unsigned short)(((int)fy << 8) | (int)fx);
            }
            ++base;
        }
    }
    __syncthreads();

    if (wv == 0) {
        const int ntiles = (M + 63) >> 6;
        const int packSent = (55 << 8) | 55;

        float qx = 3.0e38f, qy = 3.0e38f;
        int cc = packSent;
        if (lane < M) {
            float2 q = xy[lane]; qx = q.x; qy = q.y;
            cc = cellA[lane];
        }

        for (int t = 0; t < ntiles; ++t) {
            const int ts = t << 6;

            float qxN = 3.0e38f, qyN = 3.0e38f;
            int ccN = packSent;
            {
                const int p2 = ts + 64 + lane;
                if (p2 < M) {
                    float2 q = xy[p2]; qxN = q.x; qyN = q.y;
                    ccN = cellA[p2];
                }
            }

            const int cx = cc & 0xFF, cy = cc >> 8;
            const int cxm = (cx > 0) ? cx - 1 : 0;
            const int cxp = (cx < GW - 1) ? cx + 1 : GW - 1;
            const int rm  = ((cy > 0) ? cy - 1 : 0) * GW;
            const int r0  = cy * GW;
            const int rp  = ((cy < GW - 1) ? cy + 1 : GW - 1) * GW;
            const int cLin = r0 + cx;
            const int c9[9] = { rm + cxm, rm + cx, rm + cxp,
                                r0 + cxm, cLin,    r0 + cxp,
                                rp + cxm, rp + cx, rp + cxp };

            float mm = 1.0e30f;
#pragma unroll
            for (int i = 0; i < 9; ++i) {
                const int sb = c9[i] * 4;
                const float2 s0 = gslot[sb];
                const float2 s1 = gslot[sb + 1];
                const float2 s2r = gslot[sb + 2];
                const float2 s3 = gslot[sb + 3];
                float dx, dy;
                dx = qx - s0.x; dy = qy - s0.y; const float e0 = dx * dx + dy * dy;
                dx = qx - s1.x; dy = qy - s1.y; const float e1 = dx * dx + dy * dy;
                dx = qx - s2r.x; dy = qy - s2r.y; const float e2 = dx * dx + dy * dy;
                dx = qx - s3.x; dy = qy - s3.y; const float e3 = dx * dx + dy * dy;
                const float cm = fminf(fminf(e0, e1), fminf(e2, e3));
                mm = fminf(mm, cm);
            }
            const bool sup = (mm <= R2C);

            int cntT = M - ts; if (cntT > 64) cntT = 64;
            const unsigned long long tm =
                (cntT >= 64) ? ~0ull : ((1ull << cntT) - 1ull);
            unsigned long long alive = __ballot(!sup) & tm;
            unsigned long long keepm = 0ull;
            while (alive) {
                const int l = __builtin_ctzll(alive);
                const float xl = __int_as_float(
                    __builtin_amdgcn_readlane(__float_as_int(qx), l));
                const float yl = __int_as_float(
                    __builtin_amdgcn_readlane(__float_as_int(qy), l));
                const float dx = qx - xl;
                const float dy = qy - yl;
                unsigned long long b2 = __ballot((dx * dx + dy * dy) <= R2C);
                keepm |= (1ull << l);
                alive &= ~b2;
            }
            if (lane == 0) keptW[t] = keepm;

            if ((keepm >> lane) & 1ull) {
                const unsigned sh = 8u * (unsigned)(cLin & 3);
                unsigned old = atomicAdd(&cnt32[cLin >> 2], 1u << sh);
                unsigned mc = (old >> sh) & 0xFFu;
                if (mc < 4u) gslot[cLin * 4 + (int)mc] = make_float2(qx, qy);
            }

            qx = qxN; qy = qyN; cc = ccN;
        }
    }
    __syncthreads();

    int j = rank0;
#pragma unroll
    for (int k = 0; k < 8; ++k) {
        if (flags & (1 << k)) {
            if (j < M && ((keptW[j >> 6] >> (j & 63)) & 1ull)) {
                const int n = n0 + k;
                out0[2 * n]     = px[k];
                out0[2 * n + 1] = py[k];
                out1[n]         = 1.0f;
            }
            ++j;
        }
    }
}

extern "C" void kernel_launch(void* const* d_in, const int* in_sizes, int n_in,
                              void* d_out, int out_size, void* d_ws, size_t ws_size,
                              hipStream_t stream) {
    const float* seg   = (const float*)d_in[0];   // [4,4,64,128] f32
    const float* lidar = (const float*)d_in[1];   // [4,5,64,128] f32
    float* out = (float*)d_out;
    if (d_ws != nullptr && ws_size >= (size_t)WS_NEED) {
        char* ws = (char*)d_ws;
        k1_prep<<<dim3(84), dim3(1024), 0, stream>>>(seg, lidar, out, ws);
        k2_nms<<<dim3(12), dim3(1024), 0, stream>>>(ws);
        k3_scatter<<<dim3(12), dim3(1024), 0, stream>>>(out, ws);
    } else {
        radius_nms_fb<<<dim3(12), dim3(1024), 0, stream>>>(seg, lidar, out);
    }
}